// Round 1
// baseline (4184.251 us; speedup 1.0000x reference)
//
#include <hip/hip_runtime.h>

#define DCH 32
#define EPSV 1e-5f
#define SLOPE 0.01f

// ---------------- Kernel 1: fused 4-way node projection ----------------
// k = x@Wk.T+bk ; q = x@Wq.T+bq ; v = x@Wv.T+bv ; agg = x@Ws.T+bs (skip init)
__global__ __launch_bounds__(256) void k_project(
    const float* __restrict__ x,
    const float* __restrict__ Wk, const float* __restrict__ bk,
    const float* __restrict__ Wq, const float* __restrict__ bq,
    const float* __restrict__ Wv, const float* __restrict__ bv,
    const float* __restrict__ Ws, const float* __restrict__ bs,
    float* __restrict__ kout, float* __restrict__ qout,
    float* __restrict__ vout, float* __restrict__ agg,
    int N)
{
    // +1 pad on the inner dim: lane c reads w[c][d] -> bank (c*33+d)%32, conflict-free
    __shared__ float wk[DCH][DCH + 1], wq[DCH][DCH + 1], wv[DCH][DCH + 1], wsk[DCH][DCH + 1];
    __shared__ float xs[8][DCH];
    const int t = threadIdx.x;
    for (int i = t; i < DCH * DCH; i += 256) {
        const int c = i >> 5, d = i & 31;
        wk[c][d] = Wk[i];
        wq[c][d] = Wq[i];
        wv[c][d] = Wv[i];
        wsk[c][d] = Ws[i];
    }
    const int li = t >> 5;          // local node 0..7
    const int c  = t & 31;          // channel
    const int node = blockIdx.x * 8 + li;
    if (node < N) xs[li][c] = x[node * DCH + c];
    __syncthreads();
    if (node >= N) return;
    float aK = 0.f, aQ = 0.f, aV = 0.f, aS = 0.f;
    #pragma unroll
    for (int d = 0; d < DCH; ++d) {
        const float xv = xs[li][d];   // broadcast across lanes (free)
        aK += xv * wk[c][d];
        aQ += xv * wq[c][d];
        aV += xv * wv[c][d];
        aS += xv * wsk[c][d];
    }
    const int o = node * DCH + c;
    kout[o] = aK + bk[c];
    qout[o] = aQ + bq[c];
    vout[o] = aV + bv[c];
    agg[o]  = aS + bs[c];
}

// ---------------- Kernel 2: edge gather + gate + atomic scatter ----------------
// 8 lanes per edge, float4 per lane (channels 4p..4p+3).
__global__ __launch_bounds__(256) void k_edges(
    const int* __restrict__ src, const int* __restrict__ dst,
    const float4* __restrict__ k4, const float4* __restrict__ q4,
    const float4* __restrict__ v4, float* __restrict__ agg, int E)
{
    const int gid = blockIdx.x * 256 + threadIdx.x;
    const int e = gid >> 3;
    if (e >= E) return;
    const int p = threadIdx.x & 7;
    const int s = src[e];
    const int d = dst[e];
    const float4 qv = q4[(size_t)s * 8 + p];
    const float4 kv = k4[(size_t)d * 8 + p];
    const float4 vv = v4[(size_t)s * 8 + p];
    float4 eta;
    eta.x = 1.f / (1.f + __expf(-(kv.x + qv.x)));
    eta.y = 1.f / (1.f + __expf(-(kv.y + qv.y)));
    eta.z = 1.f / (1.f + __expf(-(kv.z + qv.z)));
    eta.w = 1.f / (1.f + __expf(-(kv.w + qv.w)));
    float* outp = agg + (size_t)d * DCH + p * 4;
    atomicAdd(outp + 0, eta.x * vv.x);
    atomicAdd(outp + 1, eta.y * vv.y);
    atomicAdd(outp + 2, eta.z * vv.z);
    atomicAdd(outp + 3, eta.w * vv.w);
}

// ---------------- Kernel 3: leaky + residual (in-place) + per-channel stats ----------------
__global__ __launch_bounds__(256) void k_stats(
    float* __restrict__ z,             // in: agg, out: z (in-place)
    const float* __restrict__ hin,     // residual input
    float* __restrict__ stats,         // [64]: sum[0..31], sumsq[32..63]
    int total, int do_leaky)
{
    const int t = threadIdx.x;
    float lsum = 0.f, lsq = 0.f;
    for (int i = blockIdx.x * 256 + t; i < total; i += gridDim.x * 256) {
        float v = z[i];
        if (do_leaky) v = (v >= 0.f) ? v : SLOPE * v;
        v += hin[i];
        z[i] = v;
        lsum += v;
        lsq  += v * v;
    }
    __shared__ float s1[256], s2[256];
    s1[t] = lsum; s2[t] = lsq;
    __syncthreads();
    // strides are multiples of 32 -> channel (t&31) preserved
    for (int off = 128; off >= 32; off >>= 1) {
        if (t < off) { s1[t] += s1[t + off]; s2[t] += s2[t + off]; }
        __syncthreads();
    }
    if (t < 32) {
        atomicAdd(&stats[t],      s1[t]);
        atomicAdd(&stats[32 + t], s2[t]);
    }
}

// ---------------- Kernel 4: batchnorm apply ----------------
__global__ __launch_bounds__(256) void k_bn(
    const float* __restrict__ z, const float* __restrict__ stats,
    const float* __restrict__ gamma, const float* __restrict__ beta,
    float* __restrict__ out, int total, float invN)
{
    const int i = blockIdx.x * 256 + threadIdx.x;
    if (i >= total) return;
    const int c = i & 31;
    const float mean = stats[c] * invN;
    const float var  = stats[32 + c] * invN - mean * mean;
    out[i] = (z[i] - mean) * rsqrtf(var + EPSV) * gamma[c] + beta[c];
}

extern "C" void kernel_launch(void* const* d_in, const int* in_sizes, int n_in,
                              void* d_out, int out_size, void* d_ws, size_t ws_size,
                              hipStream_t stream) {
    const float* x     = (const float*)d_in[0];
    const int*   ei    = (const int*)  d_in[1];
    // d_in[2] edge_attr: unused by the conv
    const float* Wk    = (const float*)d_in[3];
    const float* bk    = (const float*)d_in[4];
    const float* Wq    = (const float*)d_in[5];
    const float* bq    = (const float*)d_in[6];
    const float* Wv    = (const float*)d_in[7];
    const float* bv    = (const float*)d_in[8];
    const float* Ws    = (const float*)d_in[9];
    const float* bs    = (const float*)d_in[10];
    const float* gamma = (const float*)d_in[11];
    const float* beta  = (const float*)d_in[12];

    const int N = in_sizes[0] / DCH;
    const int E = in_sizes[1] / 2;
    const int* src = ei;
    const int* dst = ei + E;

    float* ws   = (float*)d_ws;
    float* kbuf = ws;
    float* qbuf = kbuf + (size_t)N * DCH;
    float* vbuf = qbuf + (size_t)N * DCH;
    float* agg  = vbuf + (size_t)N * DCH;
    float* hbuf = agg  + (size_t)N * DCH;
    float* stats = hbuf + (size_t)N * DCH;

    const int total = N * DCH;
    const float invN = 1.f / (float)N;

    const float* hin = x;
    for (int l = 0; l < 3; ++l) {
        const size_t wo = (size_t)l * DCH * DCH;
        const size_t bo = (size_t)l * DCH;
        k_project<<<(N + 7) / 8, 256, 0, stream>>>(
            hin, Wk + wo, bk + bo, Wq + wo, bq + bo, Wv + wo, bv + bo, Ws + wo, bs + bo,
            kbuf, qbuf, vbuf, agg, N);
        hipMemsetAsync(stats, 0, 64 * sizeof(float), stream);
        k_edges<<<((size_t)E * 8 + 255) / 256, 256, 0, stream>>>(
            src, dst, (const float4*)kbuf, (const float4*)qbuf, (const float4*)vbuf, agg, E);
        k_stats<<<2048, 256, 0, stream>>>(agg, hin, stats, total, (l < 2) ? 1 : 0);
        float* out_l = (l == 2) ? (float*)d_out : hbuf;
        k_bn<<<(total + 255) / 256, 256, 0, stream>>>(
            agg, stats, gamma + bo, beta + bo, out_l, total, invN);
        hin = out_l;
    }
}

// Round 2
// 1069.051 us; speedup vs baseline: 3.9140x; 3.9140x over previous
//
#include <hip/hip_runtime.h>

#define DCH 32
#define EPSV 1e-5f
#define SLOPE 0.01f
#define SSTRIDE 16      // stats stride in floats: 64B per channel slot -> no same-line atomic serialization

// ---------------- CSR build: histogram ----------------
__global__ __launch_bounds__(256) void k_hist(const int* __restrict__ dst, int* __restrict__ cnt, int E) {
    const int e = blockIdx.x * 256 + threadIdx.x;
    if (e < E) atomicAdd(&cnt[dst[e]], 1);
}

// ---------------- CSR build: single-block exclusive scan (wave-scan + cross-wave) ----------------
__global__ __launch_bounds__(1024) void k_scan(const int* __restrict__ deg, int* __restrict__ off, int N) {
    __shared__ int wsum[16];
    __shared__ int woff[16];
    __shared__ int ctot;
    __shared__ int carry;
    const int t = threadIdx.x;
    const int lane = t & 63;
    const int w = t >> 6;
    if (t == 0) carry = 0;
    __syncthreads();
    for (int base = 0; base < N; base += 1024) {
        const int i = base + t;
        const int v = (i < N) ? deg[i] : 0;
        int incl = v;
        #pragma unroll
        for (int d = 1; d < 64; d <<= 1) {
            int tmp = __shfl_up(incl, d);
            if (lane >= d) incl += tmp;
        }
        if (lane == 63) wsum[w] = incl;
        __syncthreads();
        if (t < 16) {
            const int a = wsum[t];
            int in = a;
            #pragma unroll
            for (int d = 1; d < 16; d <<= 1) {
                int tmp = __shfl_up(in, d);
                if (t >= d) in += tmp;
            }
            woff[t] = in - a;          // exclusive wave offset
            if (t == 15) ctot = in;    // chunk total
        }
        __syncthreads();
        if (i < N) off[i] = carry + woff[w] + incl - v;   // exclusive scan
        __syncthreads();
        if (t == 0) carry += ctot;
        __syncthreads();
    }
    if (t == 0) off[N] = carry;
}

// ---------------- CSR build: scatter src into dst-sorted order ----------------
__global__ __launch_bounds__(256) void k_scatter(const int* __restrict__ src, const int* __restrict__ dst,
                                                 const int* __restrict__ off, int* __restrict__ cursor,
                                                 int* __restrict__ ssrc, int E) {
    const int e = blockIdx.x * 256 + threadIdx.x;
    if (e < E) {
        const int d = dst[e];
        const int pos = atomicAdd(&cursor[d], 1);
        ssrc[off[d] + pos] = src[e];
    }
}

// ---------------- fused 4-way node projection ----------------
__global__ __launch_bounds__(256) void k_project(
    const float* __restrict__ x,
    const float* __restrict__ Wk, const float* __restrict__ bk,
    const float* __restrict__ Wq, const float* __restrict__ bq,
    const float* __restrict__ Wv, const float* __restrict__ bv,
    const float* __restrict__ Ws, const float* __restrict__ bs,
    float* __restrict__ kout, float* __restrict__ qout,
    float* __restrict__ vout, float* __restrict__ agg,
    int N)
{
    __shared__ float wk[DCH][DCH + 1], wq[DCH][DCH + 1], wv[DCH][DCH + 1], wsk[DCH][DCH + 1];
    __shared__ float xs[8][DCH];
    const int t = threadIdx.x;
    for (int i = t; i < DCH * DCH; i += 256) {
        const int c = i >> 5, d = i & 31;
        wk[c][d] = Wk[i];
        wq[c][d] = Wq[i];
        wv[c][d] = Wv[i];
        wsk[c][d] = Ws[i];
    }
    const int li = t >> 5;
    const int c  = t & 31;
    const int node = blockIdx.x * 8 + li;
    if (node < N) xs[li][c] = x[node * DCH + c];
    __syncthreads();
    if (node >= N) return;
    float aK = 0.f, aQ = 0.f, aV = 0.f, aS = 0.f;
    #pragma unroll
    for (int d = 0; d < DCH; ++d) {
        const float xv = xs[li][d];
        aK += xv * wk[c][d];
        aQ += xv * wq[c][d];
        aV += xv * wv[c][d];
        aS += xv * wsk[c][d];
    }
    const int o = node * DCH + c;
    kout[o] = aK + bk[c];
    qout[o] = aQ + bq[c];
    vout[o] = aV + bv[c];
    agg[o]  = aS + bs[c];
}

// ---------------- dst-centric edge gather + gate + fused leaky/residual/stats ----------------
// 8 lanes per node; lane p owns channels 4p..4p+3 (one float4).
__global__ __launch_bounds__(256) void k_edges_csr(
    const int* __restrict__ off, const int* __restrict__ ssrc,
    const float4* __restrict__ k4, const float4* __restrict__ q4,
    const float4* __restrict__ v4,
    const float4* __restrict__ hin4,
    float4* __restrict__ z4,              // in: skip init (from k_project), out: z
    float* __restrict__ stats, int N, int do_leaky)
{
    const int t = threadIdx.x;
    const int p = t & 7;
    const int lane = t & 63;
    const int w = t >> 6;
    const int groups = gridDim.x * 32;
    float s0 = 0.f, s1 = 0.f, s2 = 0.f, s3 = 0.f;
    float r0 = 0.f, r1 = 0.f, r2 = 0.f, r3 = 0.f;
    for (int n = blockIdx.x * 32 + (t >> 3); n < N; n += groups) {
        const int idx = n * 8 + p;
        const float4 kv = k4[idx];
        float ax = 0.f, ay = 0.f, az = 0.f, aw = 0.f;
        const int beg = off[n], end = off[n + 1];
        for (int e = beg; e < end; ++e) {
            const int s = ssrc[e];
            const float4 qv = q4[s * 8 + p];
            const float4 vv = v4[s * 8 + p];
            ax += vv.x / (1.f + __expf(-(kv.x + qv.x)));
            ay += vv.y / (1.f + __expf(-(kv.y + qv.y)));
            az += vv.z / (1.f + __expf(-(kv.z + qv.z)));
            aw += vv.w / (1.f + __expf(-(kv.w + qv.w)));
        }
        float4 z = z4[idx];               // skip connection value
        z.x += ax; z.y += ay; z.z += az; z.w += aw;
        if (do_leaky) {
            z.x = z.x >= 0.f ? z.x : SLOPE * z.x;
            z.y = z.y >= 0.f ? z.y : SLOPE * z.y;
            z.z = z.z >= 0.f ? z.z : SLOPE * z.z;
            z.w = z.w >= 0.f ? z.w : SLOPE * z.w;
        }
        const float4 hv = hin4[idx];
        z.x += hv.x; z.y += hv.y; z.z += hv.z; z.w += hv.w;
        z4[idx] = z;
        s0 += z.x; s1 += z.y; s2 += z.z; s3 += z.w;
        r0 += z.x * z.x; r1 += z.y * z.y; r2 += z.z * z.z; r3 += z.w * z.w;
    }
    // reduce across lanes sharing the same p (lane bits 3..5)
    #pragma unroll
    for (int d = 8; d < 64; d <<= 1) {
        s0 += __shfl_down(s0, d); s1 += __shfl_down(s1, d);
        s2 += __shfl_down(s2, d); s3 += __shfl_down(s3, d);
        r0 += __shfl_down(r0, d); r1 += __shfl_down(r1, d);
        r2 += __shfl_down(r2, d); r3 += __shfl_down(r3, d);
    }
    __shared__ float sm[4][DCH], sq[4][DCH];
    if (lane < 8) {
        sm[w][p * 4 + 0] = s0; sm[w][p * 4 + 1] = s1; sm[w][p * 4 + 2] = s2; sm[w][p * 4 + 3] = s3;
        sq[w][p * 4 + 0] = r0; sq[w][p * 4 + 1] = r1; sq[w][p * 4 + 2] = r2; sq[w][p * 4 + 3] = r3;
    }
    __syncthreads();
    if (t < DCH) {
        const float a = sm[0][t] + sm[1][t] + sm[2][t] + sm[3][t];
        const float b = sq[0][t] + sq[1][t] + sq[2][t] + sq[3][t];
        atomicAdd(&stats[t * SSTRIDE], a);
        atomicAdd(&stats[1024 + t * SSTRIDE], b);
    }
}

// ---------------- batchnorm apply ----------------
__global__ __launch_bounds__(256) void k_bn(
    const float* __restrict__ z, const float* __restrict__ stats,
    const float* __restrict__ gamma, const float* __restrict__ beta,
    float* __restrict__ out, int total, float invN)
{
    const int i = blockIdx.x * 256 + threadIdx.x;
    if (i >= total) return;
    const int c = i & 31;
    const float mean = stats[c * SSTRIDE] * invN;
    const float var  = stats[1024 + c * SSTRIDE] * invN - mean * mean;
    out[i] = (z[i] - mean) * rsqrtf(var + EPSV) * gamma[c] + beta[c];
}

extern "C" void kernel_launch(void* const* d_in, const int* in_sizes, int n_in,
                              void* d_out, int out_size, void* d_ws, size_t ws_size,
                              hipStream_t stream) {
    const float* x     = (const float*)d_in[0];
    const int*   ei    = (const int*)  d_in[1];
    const float* Wk    = (const float*)d_in[3];
    const float* bk    = (const float*)d_in[4];
    const float* Wq    = (const float*)d_in[5];
    const float* bq    = (const float*)d_in[6];
    const float* Wv    = (const float*)d_in[7];
    const float* bv    = (const float*)d_in[8];
    const float* Ws    = (const float*)d_in[9];
    const float* bs    = (const float*)d_in[10];
    const float* gamma = (const float*)d_in[11];
    const float* beta  = (const float*)d_in[12];

    const int N = in_sizes[0] / DCH;
    const int E = in_sizes[1] / 2;
    const int* src = ei;
    const int* dst = ei + E;

    float* ws    = (float*)d_ws;
    float* kbuf  = ws;
    float* qbuf  = kbuf + (size_t)N * DCH;
    float* vbuf  = qbuf + (size_t)N * DCH;
    float* agg   = vbuf + (size_t)N * DCH;   // skip-init, then z (in place)
    float* hbuf  = agg  + (size_t)N * DCH;
    float* stats = hbuf + (size_t)N * DCH;   // 2048 floats (padded)
    int*   ioff   = (int*)(stats + 2048);    // N+1
    int*   cursor = ioff + (N + 1);          // N (doubles as degree histogram)
    int*   ssrc   = cursor + N;              // E

    const int total = N * DCH;
    const float invN = 1.f / (float)N;

    // ---- build CSR once (reused by all 3 layers) ----
    hipMemsetAsync(cursor, 0, (size_t)N * sizeof(int), stream);
    k_hist<<<(E + 255) / 256, 256, 0, stream>>>(dst, cursor, E);
    k_scan<<<1, 1024, 0, stream>>>(cursor, ioff, N);
    hipMemsetAsync(cursor, 0, (size_t)N * sizeof(int), stream);
    k_scatter<<<(E + 255) / 256, 256, 0, stream>>>(src, dst, ioff, cursor, ssrc, E);

    const float* hin = x;
    for (int l = 0; l < 3; ++l) {
        const size_t wo = (size_t)l * DCH * DCH;
        const size_t bo = (size_t)l * DCH;
        k_project<<<(N + 7) / 8, 256, 0, stream>>>(
            hin, Wk + wo, bk + bo, Wq + wo, bq + bo, Wv + wo, bv + bo, Ws + wo, bs + bo,
            kbuf, qbuf, vbuf, agg, N);
        hipMemsetAsync(stats, 0, 2048 * sizeof(float), stream);
        k_edges_csr<<<1024, 256, 0, stream>>>(
            ioff, ssrc, (const float4*)kbuf, (const float4*)qbuf, (const float4*)vbuf,
            (const float4*)hin, (float4*)agg, stats, N, (l < 2) ? 1 : 0);
        float* out_l = (l == 2) ? (float*)d_out : hbuf;
        k_bn<<<(total + 255) / 256, 256, 0, stream>>>(
            agg, stats, gamma + bo, beta + bo, out_l, total, invN);
        hin = out_l;
    }
}

// Round 3
// 901.990 us; speedup vs baseline: 4.6389x; 1.1852x over previous
//
#include <hip/hip_runtime.h>

#define DCH 32
#define EPSV 1e-5f
#define SLOPE 0.01f
#define SSTRIDE 16      // stats stride in floats (64B/channel slot)

__device__ __forceinline__ unsigned short f2bf(float x) {
    unsigned u = __float_as_uint(x);
    unsigned r = (u + 0x7FFFu + ((u >> 16) & 1u)) >> 16;   // round-to-nearest-even
    return (unsigned short)r;
}
__device__ __forceinline__ float bf2f(unsigned short u) {
    return __uint_as_float(((unsigned)u) << 16);
}

// ---------------- CSR build: histogram ----------------
__global__ __launch_bounds__(256) void k_hist(const int* __restrict__ dst, int* __restrict__ cnt, int E) {
    const int e = blockIdx.x * 256 + threadIdx.x;
    if (e < E) atomicAdd(&cnt[dst[e]], 1);
}

// ---------------- CSR build: parallel block scan, block base via one atomicAdd ----------------
// Segment ordering across blocks is nondeterministic but CSR stays valid
// (consumers read off[n] and deg[n], never off[n+1]).
__global__ __launch_bounds__(1024) void k_scan_atomic(const int* __restrict__ deg, int* __restrict__ off,
                                                      int* __restrict__ gtot, int N) {
    __shared__ int wsum[16];
    __shared__ int woff[16];
    __shared__ int base_sh;
    const int t = threadIdx.x;
    const int lane = t & 63;
    const int w = t >> 6;
    const int i = blockIdx.x * 1024 + t;
    const int v = (i < N) ? deg[i] : 0;
    int incl = v;
    #pragma unroll
    for (int d = 1; d < 64; d <<= 1) {
        int tmp = __shfl_up(incl, d);
        if (lane >= d) incl += tmp;
    }
    if (lane == 63) wsum[w] = incl;
    __syncthreads();
    if (t < 16) {
        const int a = wsum[t];
        int in = a;
        #pragma unroll
        for (int d = 1; d < 16; d <<= 1) {
            int tmp = __shfl_up(in, d);
            if (t >= d) in += tmp;
        }
        woff[t] = in - a;
        if (t == 15) base_sh = atomicAdd(gtot, in);
    }
    __syncthreads();
    if (i < N) off[i] = base_sh + woff[w] + incl - v;
}

// ---------------- CSR build: scatter src into dst-grouped order ----------------
__global__ __launch_bounds__(256) void k_scatter(const int* __restrict__ src, const int* __restrict__ dst,
                                                 const int* __restrict__ off, int* __restrict__ cursor,
                                                 int* __restrict__ ssrc, int E) {
    const int e = blockIdx.x * 256 + threadIdx.x;
    if (e < E) {
        const int d = dst[e];
        const int pos = atomicAdd(&cursor[d], 1);
        ssrc[off[d] + pos] = src[e];
    }
}

// ---------------- fused: [BN of prev layer] + 4-way projection ----------------
// kout f32; q,v packed bf16 interleaved per 4-channel group: per node 128B =
// 8 lanes x {q[4p..4p+3], v[4p..4p+3]} as 8x bf16. zout gets the skip init.
__global__ __launch_bounds__(256) void k_project(
    const float* __restrict__ xin,           // prev z (pre-BN) or x when do_bn==0
    const float* __restrict__ statsPrev, const float* __restrict__ gPrev, const float* __restrict__ bPrev,
    const float* __restrict__ Wk, const float* __restrict__ bk,
    const float* __restrict__ Wq, const float* __restrict__ bq,
    const float* __restrict__ Wv, const float* __restrict__ bv,
    const float* __restrict__ Ws, const float* __restrict__ bs,
    float* __restrict__ kout, unsigned short* __restrict__ qvout,
    float* __restrict__ zout,
    int N, int do_bn, float invN)
{
    __shared__ float wk[DCH][DCH + 1], wq[DCH][DCH + 1], wv[DCH][DCH + 1], wsk[DCH][DCH + 1];
    __shared__ float xs[8][DCH];
    const int t = threadIdx.x;
    for (int i = t; i < DCH * DCH; i += 256) {
        const int c = i >> 5, d = i & 31;
        wk[c][d] = Wk[i];
        wq[c][d] = Wq[i];
        wv[c][d] = Wv[i];
        wsk[c][d] = Ws[i];
    }
    const int li = t >> 5;
    const int c  = t & 31;
    const int node = blockIdx.x * 8 + li;
    if (node < N) {
        float xv = xin[node * DCH + c];
        if (do_bn) {
            const float mn = statsPrev[c * SSTRIDE] * invN;
            const float var = statsPrev[1024 + c * SSTRIDE] * invN - mn * mn;
            const float sc = rsqrtf(var + EPSV) * gPrev[c];
            xv = (xv - mn) * sc + bPrev[c];
        }
        xs[li][c] = xv;
    }
    __syncthreads();
    if (node >= N) return;
    float aK = 0.f, aQ = 0.f, aV = 0.f, aS = 0.f;
    #pragma unroll
    for (int d = 0; d < DCH; ++d) {
        const float xv = xs[li][d];
        aK += xv * wk[c][d];
        aQ += xv * wq[c][d];
        aV += xv * wv[c][d];
        aS += xv * wsk[c][d];
    }
    const int o = node * DCH + c;
    kout[o] = aK + bk[c];
    zout[o] = aS + bs[c];
    const int qb = node * 64 + (c >> 2) * 8 + (c & 3);
    qvout[qb]     = f2bf(aQ + bq[c]);
    qvout[qb + 4] = f2bf(aV + bv[c]);
}

// ---------------- dst-centric gather + gate + fused [BN(prev) residual]/leaky/stats ----------------
// 8 lanes per node; lane p owns channels 4p..4p+3.
__global__ __launch_bounds__(256) void k_edges_csr(
    const int* __restrict__ off, const int* __restrict__ deg, const int* __restrict__ ssrc,
    const float4* __restrict__ k4, const float4* __restrict__ qv4,
    const float4* __restrict__ zprev4,       // prev z (pre-BN) or x when do_bn==0
    const float* __restrict__ statsPrev, const float* __restrict__ gPrev, const float* __restrict__ bPrev,
    float4* __restrict__ z4,                 // in: skip init, out: z
    float* __restrict__ statsCur, int N, int do_leaky, int do_bn, float invN)
{
    const int t = threadIdx.x;
    const int p = t & 7;
    const int lane = t & 63;
    const int w = t >> 6;
    const int groups = gridDim.x * 32;
    // per-lane BN coefficients of the previous layer (h = z*scv + shv)
    float scv[4] = {1.f, 1.f, 1.f, 1.f}, shv[4] = {0.f, 0.f, 0.f, 0.f};
    if (do_bn) {
        #pragma unroll
        for (int j = 0; j < 4; ++j) {
            const int c = p * 4 + j;
            const float mn = statsPrev[c * SSTRIDE] * invN;
            const float var = statsPrev[1024 + c * SSTRIDE] * invN - mn * mn;
            const float rs = rsqrtf(var + EPSV) * gPrev[c];
            scv[j] = rs;
            shv[j] = bPrev[c] - mn * rs;
        }
    }
    float s0 = 0.f, s1 = 0.f, s2 = 0.f, s3 = 0.f;
    float r0 = 0.f, r1 = 0.f, r2 = 0.f, r3 = 0.f;
    for (int n = blockIdx.x * 32 + (t >> 3); n < N; n += groups) {
        const int idx = n * 8 + p;
        const float4 kv = k4[idx];
        float ax = 0.f, ay = 0.f, az = 0.f, aw = 0.f;
        const int beg = off[n];
        const int end = beg + deg[n];
        for (int e = beg; e < end; ++e) {
            const int s = ssrc[e];
            union { float4 f; unsigned short us[8]; } U;
            U.f = qv4[(size_t)s * 8 + p];
            const float q0 = bf2f(U.us[0]), q1 = bf2f(U.us[1]), q2 = bf2f(U.us[2]), q3 = bf2f(U.us[3]);
            const float v0 = bf2f(U.us[4]), v1 = bf2f(U.us[5]), v2 = bf2f(U.us[6]), v3 = bf2f(U.us[7]);
            ax += v0 / (1.f + __expf(-(kv.x + q0)));
            ay += v1 / (1.f + __expf(-(kv.y + q1)));
            az += v2 / (1.f + __expf(-(kv.z + q2)));
            aw += v3 / (1.f + __expf(-(kv.w + q3)));
        }
        float4 z = z4[idx];                  // skip value
        z.x += ax; z.y += ay; z.z += az; z.w += aw;
        if (do_leaky) {
            z.x = z.x >= 0.f ? z.x : SLOPE * z.x;
            z.y = z.y >= 0.f ? z.y : SLOPE * z.y;
            z.z = z.z >= 0.f ? z.z : SLOPE * z.z;
            z.w = z.w >= 0.f ? z.w : SLOPE * z.w;
        }
        const float4 hz = zprev4[idx];
        z.x += hz.x * scv[0] + shv[0];
        z.y += hz.y * scv[1] + shv[1];
        z.z += hz.z * scv[2] + shv[2];
        z.w += hz.w * scv[3] + shv[3];
        z4[idx] = z;
        s0 += z.x; s1 += z.y; s2 += z.z; s3 += z.w;
        r0 += z.x * z.x; r1 += z.y * z.y; r2 += z.z * z.z; r3 += z.w * z.w;
    }
    #pragma unroll
    for (int d = 8; d < 64; d <<= 1) {
        s0 += __shfl_down(s0, d); s1 += __shfl_down(s1, d);
        s2 += __shfl_down(s2, d); s3 += __shfl_down(s3, d);
        r0 += __shfl_down(r0, d); r1 += __shfl_down(r1, d);
        r2 += __shfl_down(r2, d); r3 += __shfl_down(r3, d);
    }
    __shared__ float sm[4][DCH], sq[4][DCH];
    if (lane < 8) {
        sm[w][p * 4 + 0] = s0; sm[w][p * 4 + 1] = s1; sm[w][p * 4 + 2] = s2; sm[w][p * 4 + 3] = s3;
        sq[w][p * 4 + 0] = r0; sq[w][p * 4 + 1] = r1; sq[w][p * 4 + 2] = r2; sq[w][p * 4 + 3] = r3;
    }
    __syncthreads();
    if (t < DCH) {
        const float a = sm[0][t] + sm[1][t] + sm[2][t] + sm[3][t];
        const float b = sq[0][t] + sq[1][t] + sq[2][t] + sq[3][t];
        atomicAdd(&statsCur[t * SSTRIDE], a);
        atomicAdd(&statsCur[1024 + t * SSTRIDE], b);
    }
}

// ---------------- final batchnorm apply ----------------
__global__ __launch_bounds__(256) void k_bn(
    const float* __restrict__ z, const float* __restrict__ stats,
    const float* __restrict__ gamma, const float* __restrict__ beta,
    float* __restrict__ out, int total, float invN)
{
    const int i = blockIdx.x * 256 + threadIdx.x;
    if (i >= total) return;
    const int c = i & 31;
    const float mean = stats[c * SSTRIDE] * invN;
    const float var  = stats[1024 + c * SSTRIDE] * invN - mean * mean;
    out[i] = (z[i] - mean) * rsqrtf(var + EPSV) * gamma[c] + beta[c];
}

extern "C" void kernel_launch(void* const* d_in, const int* in_sizes, int n_in,
                              void* d_out, int out_size, void* d_ws, size_t ws_size,
                              hipStream_t stream) {
    const float* x     = (const float*)d_in[0];
    const int*   ei    = (const int*)  d_in[1];
    const float* Wk    = (const float*)d_in[3];
    const float* bk    = (const float*)d_in[4];
    const float* Wq    = (const float*)d_in[5];
    const float* bq    = (const float*)d_in[6];
    const float* Wv    = (const float*)d_in[7];
    const float* bv    = (const float*)d_in[8];
    const float* Ws    = (const float*)d_in[9];
    const float* bs    = (const float*)d_in[10];
    const float* gamma = (const float*)d_in[11];
    const float* beta  = (const float*)d_in[12];

    const int N = in_sizes[0] / DCH;
    const int E = in_sizes[1] / 2;
    const int* src = ei;
    const int* dst = ei + E;

    float* ws     = (float*)d_ws;
    float* kbuf   = ws;                              // N*32 f32
    unsigned short* qvbuf = (unsigned short*)(kbuf + (size_t)N * DCH);  // N*64 u16 (N*32 f32 bytes)
    float* zA     = (float*)qvbuf + (size_t)N * DCH; // N*32
    float* zB     = zA + (size_t)N * DCH;            // N*32
    float* statsA = zB + (size_t)N * DCH;            // 2048
    float* statsB = statsA + 2048;                   // 2048
    int*   deg    = (int*)(statsB + 2048);           // N
    int*   offb   = deg + N;                         // N
    int*   cursor = offb + N;                        // N
    int*   gtot   = cursor + N;                      // 1
    int*   ssrc   = gtot + 4;                        // E

    const int total = N * DCH;
    const float invN = 1.f / (float)N;

    // ---- build CSR once per launch (reused by all 3 layers) ----
    hipMemsetAsync(deg, 0, (size_t)N * sizeof(int), stream);
    hipMemsetAsync(gtot, 0, sizeof(int), stream);
    k_hist<<<(E + 255) / 256, 256, 0, stream>>>(dst, deg, E);
    k_scan_atomic<<<(N + 1023) / 1024, 1024, 0, stream>>>(deg, offb, gtot, N);
    hipMemsetAsync(cursor, 0, (size_t)N * sizeof(int), stream);
    k_scatter<<<(E + 255) / 256, 256, 0, stream>>>(src, dst, offb, cursor, ssrc, E);

    const float* zprev = x;          // pre-BN input to current layer (x for l=0)
    const float* statsPrev = nullptr;
    for (int l = 0; l < 3; ++l) {
        const size_t wo = (size_t)l * DCH * DCH;
        const size_t bo = (size_t)l * DCH;
        float* zcur = (l & 1) ? zB : zA;
        float* statsCur = (l & 1) ? statsB : statsA;
        const float* gPrev = (l > 0) ? gamma + (size_t)(l - 1) * DCH : gamma;
        const float* bPrev = (l > 0) ? beta + (size_t)(l - 1) * DCH : beta;
        const int do_bn = (l > 0) ? 1 : 0;
        const float* sPrev = do_bn ? statsPrev : statsA;   // dummy ptr when unused

        k_project<<<(N + 7) / 8, 256, 0, stream>>>(
            zprev, sPrev, gPrev, bPrev,
            Wk + wo, bk + bo, Wq + wo, bq + bo, Wv + wo, bv + bo, Ws + wo, bs + bo,
            kbuf, qvbuf, zcur, N, do_bn, invN);
        hipMemsetAsync(statsCur, 0, 2048 * sizeof(float), stream);
        k_edges_csr<<<1024, 256, 0, stream>>>(
            offb, deg, ssrc, (const float4*)kbuf, (const float4*)qvbuf,
            (const float4*)zprev, sPrev, gPrev, bPrev,
            (float4*)zcur, statsCur, N, (l < 2) ? 1 : 0, do_bn, invN);

        statsPrev = statsCur;
        zprev = zcur;
    }
    // final BN -> d_out (layer 2: zA, statsA)
    k_bn<<<(total + 255) / 256, 256, 0, stream>>>(
        zA, statsA, gamma + 2 * DCH, beta + 2 * DCH, (float*)d_out, total, invN);
}

// Round 4
// 542.330 us; speedup vs baseline: 7.7153x; 1.6632x over previous
//
#include <hip/hip_runtime.h>

#define DCH 32
#define EPSV 1e-5f
#define SLOPE 0.01f
#define SSTRIDE 16       // stats stride in floats (64B/channel slot)
#define BSH 7            // bucket shift: 128 nodes per bucket
#define BSZ 128
#define NBMAX 1024       // max buckets handled by LDS paths (N <= 131072)
#define CHUNK 8192       // edges per block in hist/scatter
#define CAP 6144         // max edges per bucket for LDS-staged CSR build

__device__ __forceinline__ unsigned short f2bf(float x) {
    unsigned u = __float_as_uint(x);
    unsigned r = (u + 0x7FFFu + ((u >> 16) & 1u)) >> 16;   // RNE
    return (unsigned short)r;
}
__device__ __forceinline__ float bf2f(unsigned short u) {
    return __uint_as_float(((unsigned)u) << 16);
}

// ---------------- bucket histogram (LDS-staged) ----------------
__global__ __launch_bounds__(256) void k_bucket_hist(const int* __restrict__ dst,
                                                     int* __restrict__ bcnt, int E, int NB) {
    __shared__ int h[NBMAX];
    const int t = threadIdx.x;
    const int e0 = blockIdx.x * CHUNK;
    const int e1 = min(e0 + CHUNK, E);
    if (NB <= NBMAX) {
        for (int j = t; j < NB; j += 256) h[j] = 0;
        __syncthreads();
        for (int e = e0 + t; e < e1; e += 256) atomicAdd(&h[dst[e] >> BSH], 1);
        __syncthreads();
        for (int j = t; j < NB; j += 256) if (h[j]) atomicAdd(&bcnt[j], h[j]);
    } else {
        for (int e = e0 + t; e < e1; e += 256) atomicAdd(&bcnt[dst[e] >> BSH], 1);
    }
}

// ---------------- single-block chunked exclusive scan (M values -> off[0..M]) ----------------
__global__ __launch_bounds__(1024) void k_scan(const int* __restrict__ deg, int* __restrict__ off, int N) {
    __shared__ int wsum[16];
    __shared__ int woff[16];
    __shared__ int ctot;
    __shared__ int carry;
    const int t = threadIdx.x;
    const int lane = t & 63;
    const int w = t >> 6;
    if (t == 0) carry = 0;
    __syncthreads();
    for (int base = 0; base < N; base += 1024) {
        const int i = base + t;
        const int v = (i < N) ? deg[i] : 0;
        int incl = v;
        #pragma unroll
        for (int d = 1; d < 64; d <<= 1) {
            int tmp = __shfl_up(incl, d);
            if (lane >= d) incl += tmp;
        }
        if (lane == 63) wsum[w] = incl;
        __syncthreads();
        if (t < 16) {
            const int a = wsum[t];
            int in = a;
            #pragma unroll
            for (int d = 1; d < 16; d <<= 1) {
                int tmp = __shfl_up(in, d);
                if (t >= d) in += tmp;
            }
            woff[t] = in - a;
            if (t == 15) ctot = in;
        }
        __syncthreads();
        if (i < N) off[i] = carry + woff[w] + incl - v;
        __syncthreads();
        if (t == 0) carry += ctot;
        __syncthreads();
    }
    if (t == 0) off[N] = carry;
}

// ---------------- bucket scatter: packed (src<<7)|dst_local into bucket-grouped runs ----------------
__global__ __launch_bounds__(256) void k_bucket_scatter(const int* __restrict__ src, const int* __restrict__ dst,
                                                        const int* __restrict__ boff, int* __restrict__ cur,
                                                        unsigned int* __restrict__ pairs, int E, int NB) {
    const int t = threadIdx.x;
    const int e0 = blockIdx.x * CHUNK;
    const int e1 = min(e0 + CHUNK, E);
    if (NB <= NBMAX) {
        __shared__ int cnt[NBMAX];
        __shared__ int base[NBMAX];
        for (int j = t; j < NB; j += 256) { cnt[j] = 0; }
        __syncthreads();
        for (int e = e0 + t; e < e1; e += 256) atomicAdd(&cnt[dst[e] >> BSH], 1);
        __syncthreads();
        for (int j = t; j < NB; j += 256) {
            const int c = cnt[j];
            if (c) base[j] = atomicAdd(&cur[j], c);
            cnt[j] = 0;          // reuse as rank counter
        }
        __syncthreads();
        for (int e = e0 + t; e < e1; e += 256) {
            const int d = dst[e];
            const int bk = d >> BSH;
            const int r = atomicAdd(&cnt[bk], 1);
            pairs[boff[bk] + base[bk] + r] = ((unsigned)src[e] << BSH) | (unsigned)(d & (BSZ - 1));
        }
    } else {
        for (int e = e0 + t; e < e1; e += 256) {
            const int d = dst[e];
            const int bk = d >> BSH;
            const int r = atomicAdd(&cur[bk], 1);
            pairs[boff[bk] + r] = ((unsigned)src[e] << BSH) | (unsigned)(d & (BSZ - 1));
        }
    }
}

// ---------------- per-bucket CSR build: node histogram + scan + dense ssrc ----------------
__global__ __launch_bounds__(256) void k_build_csr(const unsigned int* __restrict__ pairs,
                                                   const int* __restrict__ boff,
                                                   int* __restrict__ deg, int* __restrict__ off,
                                                   int* __restrict__ ssrc, int N) {
    __shared__ int cnt[BSZ];
    __shared__ int scn[BSZ];
    __shared__ int rnk[BSZ];
    __shared__ int stage[CAP];
    const int t = threadIdx.x;
    const int b = blockIdx.x;
    const int begin = boff[b], end = boff[b + 1];
    const int total = end - begin;
    if (t < BSZ) { cnt[t] = 0; rnk[t] = 0; }
    __syncthreads();
    for (int i = begin + t; i < end; i += 256) atomicAdd(&cnt[pairs[i] & (BSZ - 1)], 1);
    __syncthreads();
    if (t < BSZ) scn[t] = cnt[t];
    __syncthreads();
    #pragma unroll
    for (int s = 1; s < BSZ; s <<= 1) {
        int add = 0;
        if (t < BSZ && t >= s) add = scn[t - s];
        __syncthreads();
        if (t < BSZ) scn[t] += add;
        __syncthreads();
    }
    // scn = inclusive; exclusive = scn - cnt
    const int node0 = b << BSH;
    if (t < BSZ && node0 + t < N) {
        deg[node0 + t] = cnt[t];
        off[node0 + t] = begin + scn[t] - cnt[t];
    }
    if (total <= CAP) {
        for (int i = begin + t; i < end; i += 256) {
            const unsigned u = pairs[i];
            const int nl = u & (BSZ - 1);
            const int r = atomicAdd(&rnk[nl], 1);
            stage[scn[nl] - cnt[nl] + r] = (int)(u >> BSH);
        }
        __syncthreads();
        for (int i = t; i < total; i += 256) ssrc[begin + i] = stage[i];
    } else {
        for (int i = begin + t; i < end; i += 256) {
            const unsigned u = pairs[i];
            const int nl = u & (BSZ - 1);
            const int r = atomicAdd(&rnk[nl], 1);
            ssrc[begin + scn[nl] - cnt[nl] + r] = (int)(u >> BSH);
        }
    }
}

// ---------------- fused: [BN of prev layer] + 4-way projection ----------------
// kout f32; q,v packed bf16: per node 128B = 8 groups x {q[4c], v[4c]} bf16.
__global__ __launch_bounds__(256) void k_project(
    const float* __restrict__ xin,
    const float* __restrict__ statsPrev, const float* __restrict__ gPrev, const float* __restrict__ bPrev,
    const float* __restrict__ Wk, const float* __restrict__ bk,
    const float* __restrict__ Wq, const float* __restrict__ bq,
    const float* __restrict__ Wv, const float* __restrict__ bv,
    const float* __restrict__ Ws, const float* __restrict__ bs,
    float* __restrict__ kout, uint4* __restrict__ qvout,
    float* __restrict__ zout,
    int N, int do_bn, float invN)
{
    __shared__ float wk[DCH][DCH + 1], wq[DCH][DCH + 1], wv[DCH][DCH + 1], wsk[DCH][DCH + 1];
    __shared__ float xs[8][DCH];
    __shared__ unsigned short qvs[8][64];
    const int t = threadIdx.x;
    for (int i = t; i < DCH * DCH; i += 256) {
        const int c = i >> 5, d = i & 31;
        wk[c][d] = Wk[i];
        wq[c][d] = Wq[i];
        wv[c][d] = Wv[i];
        wsk[c][d] = Ws[i];
    }
    const int li = t >> 5;
    const int c  = t & 31;
    const int node = blockIdx.x * 8 + li;
    if (node < N) {
        float xv = xin[node * DCH + c];
        if (do_bn) {
            const float mn = statsPrev[c * SSTRIDE] * invN;
            const float var = statsPrev[1024 + c * SSTRIDE] * invN - mn * mn;
            const float sc = rsqrtf(var + EPSV) * gPrev[c];
            xv = (xv - mn) * sc + bPrev[c];
        }
        xs[li][c] = xv;
    }
    __syncthreads();
    float aK = 0.f, aQ = 0.f, aV = 0.f, aS = 0.f;
    if (node < N) {
        #pragma unroll
        for (int d = 0; d < DCH; ++d) {
            const float xv = xs[li][d];
            aK += xv * wk[c][d];
            aQ += xv * wq[c][d];
            aV += xv * wv[c][d];
            aS += xv * wsk[c][d];
        }
        const int o = node * DCH + c;
        kout[o] = aK + bk[c];
        zout[o] = aS + bs[c];
        const int g = c >> 2, j = c & 3;
        qvs[li][g * 8 + j]     = f2bf(aQ + bq[c]);
        qvs[li][g * 8 + 4 + j] = f2bf(aV + bv[c]);
    }
    __syncthreads();
    // flush qv: 8 nodes x 8 uint4 = 64 stores
    if (t < 64) {
        const int ln = t >> 3, g = t & 7;
        const int nd = blockIdx.x * 8 + ln;
        if (nd < N) qvout[nd * 8 + g] = ((const uint4*)qvs[ln])[g];
    }
}

// ---------------- dst-centric gather + gate + fused [BN(prev) residual]/leaky/stats ----------------
__global__ __launch_bounds__(256) void k_edges_csr(
    const int* __restrict__ off, const int* __restrict__ deg, const int* __restrict__ ssrc,
    const float4* __restrict__ k4, const float4* __restrict__ qv4,
    const float4* __restrict__ zprev4,
    const float* __restrict__ statsPrev, const float* __restrict__ gPrev, const float* __restrict__ bPrev,
    float4* __restrict__ z4,
    float* __restrict__ statsCur, int N, int do_leaky, int do_bn, float invN)
{
    const int t = threadIdx.x;
    const int p = t & 7;
    const int lane = t & 63;
    const int w = t >> 6;
    const int groups = gridDim.x * 32;
    float scv[4] = {1.f, 1.f, 1.f, 1.f}, shv[4] = {0.f, 0.f, 0.f, 0.f};
    if (do_bn) {
        #pragma unroll
        for (int j = 0; j < 4; ++j) {
            const int c = p * 4 + j;
            const float mn = statsPrev[c * SSTRIDE] * invN;
            const float var = statsPrev[1024 + c * SSTRIDE] * invN - mn * mn;
            const float rs = rsqrtf(var + EPSV) * gPrev[c];
            scv[j] = rs;
            shv[j] = bPrev[c] - mn * rs;
        }
    }
    float s0 = 0.f, s1 = 0.f, s2 = 0.f, s3 = 0.f;
    float r0 = 0.f, r1 = 0.f, r2 = 0.f, r3 = 0.f;
    for (int n = blockIdx.x * 32 + (t >> 3); n < N; n += groups) {
        const int idx = n * 8 + p;
        const float4 kv = k4[idx];
        float ax = 0.f, ay = 0.f, az = 0.f, aw = 0.f;
        const int beg = off[n];
        const int end = beg + deg[n];
        for (int e = beg; e < end; ++e) {
            const int s = ssrc[e];
            union { float4 f; unsigned short us[8]; } U;
            U.f = qv4[(size_t)s * 8 + p];
            ax += bf2f(U.us[4]) / (1.f + __expf(-(kv.x + bf2f(U.us[0]))));
            ay += bf2f(U.us[5]) / (1.f + __expf(-(kv.y + bf2f(U.us[1]))));
            az += bf2f(U.us[6]) / (1.f + __expf(-(kv.z + bf2f(U.us[2]))));
            aw += bf2f(U.us[7]) / (1.f + __expf(-(kv.w + bf2f(U.us[3]))));
        }
        float4 z = z4[idx];
        z.x += ax; z.y += ay; z.z += az; z.w += aw;
        if (do_leaky) {
            z.x = z.x >= 0.f ? z.x : SLOPE * z.x;
            z.y = z.y >= 0.f ? z.y : SLOPE * z.y;
            z.z = z.z >= 0.f ? z.z : SLOPE * z.z;
            z.w = z.w >= 0.f ? z.w : SLOPE * z.w;
        }
        const float4 hz = zprev4[idx];
        z.x += hz.x * scv[0] + shv[0];
        z.y += hz.y * scv[1] + shv[1];
        z.z += hz.z * scv[2] + shv[2];
        z.w += hz.w * scv[3] + shv[3];
        z4[idx] = z;
        s0 += z.x; s1 += z.y; s2 += z.z; s3 += z.w;
        r0 += z.x * z.x; r1 += z.y * z.y; r2 += z.z * z.z; r3 += z.w * z.w;
    }
    #pragma unroll
    for (int d = 8; d < 64; d <<= 1) {
        s0 += __shfl_down(s0, d); s1 += __shfl_down(s1, d);
        s2 += __shfl_down(s2, d); s3 += __shfl_down(s3, d);
        r0 += __shfl_down(r0, d); r1 += __shfl_down(r1, d);
        r2 += __shfl_down(r2, d); r3 += __shfl_down(r3, d);
    }
    __shared__ float sm[4][DCH], sq[4][DCH];
    if (lane < 8) {
        sm[w][p * 4 + 0] = s0; sm[w][p * 4 + 1] = s1; sm[w][p * 4 + 2] = s2; sm[w][p * 4 + 3] = s3;
        sq[w][p * 4 + 0] = r0; sq[w][p * 4 + 1] = r1; sq[w][p * 4 + 2] = r2; sq[w][p * 4 + 3] = r3;
    }
    __syncthreads();
    if (t < DCH) {
        const float a = sm[0][t] + sm[1][t] + sm[2][t] + sm[3][t];
        const float b = sq[0][t] + sq[1][t] + sq[2][t] + sq[3][t];
        atomicAdd(&statsCur[t * SSTRIDE], a);
        atomicAdd(&statsCur[1024 + t * SSTRIDE], b);
    }
}

// ---------------- final batchnorm apply ----------------
__global__ __launch_bounds__(256) void k_bn(
    const float* __restrict__ z, const float* __restrict__ stats,
    const float* __restrict__ gamma, const float* __restrict__ beta,
    float* __restrict__ out, int total, float invN)
{
    const int i = blockIdx.x * 256 + threadIdx.x;
    if (i >= total) return;
    const int c = i & 31;
    const float mean = stats[c * SSTRIDE] * invN;
    const float var  = stats[1024 + c * SSTRIDE] * invN - mean * mean;
    out[i] = (z[i] - mean) * rsqrtf(var + EPSV) * gamma[c] + beta[c];
}

extern "C" void kernel_launch(void* const* d_in, const int* in_sizes, int n_in,
                              void* d_out, int out_size, void* d_ws, size_t ws_size,
                              hipStream_t stream) {
    const float* x     = (const float*)d_in[0];
    const int*   ei    = (const int*)  d_in[1];
    const float* Wk    = (const float*)d_in[3];
    const float* bk    = (const float*)d_in[4];
    const float* Wq    = (const float*)d_in[5];
    const float* bq    = (const float*)d_in[6];
    const float* Wv    = (const float*)d_in[7];
    const float* bv    = (const float*)d_in[8];
    const float* Ws    = (const float*)d_in[9];
    const float* bs    = (const float*)d_in[10];
    const float* gamma = (const float*)d_in[11];
    const float* beta  = (const float*)d_in[12];

    const int N = in_sizes[0] / DCH;
    const int E = in_sizes[1] / 2;
    const int NB = (N + BSZ - 1) >> BSH;
    const int* src = ei;
    const int* dst = ei + E;

    float* ws     = (float*)d_ws;
    float* kbuf   = ws;                                   // N*32 f32
    unsigned short* qvbuf = (unsigned short*)(kbuf + (size_t)N * DCH);   // N*64 u16
    float* zA     = (float*)qvbuf + (size_t)N * DCH;      // N*32 f32
    float* zB     = zA + (size_t)N * DCH;
    float* statsA = zB + (size_t)N * DCH;                 // 2048
    float* statsB = statsA + 2048;                        // 2048
    int*   deg    = (int*)(statsB + 2048);                // N
    int*   off    = deg + N;                              // N
    int*   bcnt   = off + N;                              // NB
    int*   boff   = bcnt + NB;                            // NB+1
    int*   cur    = boff + NB + 1;                        // NB
    unsigned int* pairs = (unsigned int*)(cur + NB);      // E
    int*   ssrc   = (int*)(pairs + E);                    // E

    const int total = N * DCH;
    const float invN = 1.f / (float)N;

    // ---- build CSR once per launch ----
    hipMemsetAsync(bcnt, 0, (size_t)NB * sizeof(int), stream);
    hipMemsetAsync(cur, 0, (size_t)NB * sizeof(int), stream);
    const int nchunk = (E + CHUNK - 1) / CHUNK;
    k_bucket_hist<<<nchunk, 256, 0, stream>>>(dst, bcnt, E, NB);
    k_scan<<<1, 1024, 0, stream>>>(bcnt, boff, NB);
    k_bucket_scatter<<<nchunk, 256, 0, stream>>>(src, dst, boff, cur, pairs, E, NB);
    k_build_csr<<<NB, 256, 0, stream>>>(pairs, boff, deg, off, ssrc, N);

    const float* zprev = x;
    const float* statsPrev = nullptr;
    for (int l = 0; l < 3; ++l) {
        const size_t wo = (size_t)l * DCH * DCH;
        const size_t bo = (size_t)l * DCH;
        float* zcur = (l & 1) ? zB : zA;
        float* statsCur = (l & 1) ? statsB : statsA;
        const float* gPrev = (l > 0) ? gamma + (size_t)(l - 1) * DCH : gamma;
        const float* bPrev = (l > 0) ? beta + (size_t)(l - 1) * DCH : beta;
        const int do_bn = (l > 0) ? 1 : 0;
        const float* sPrev = do_bn ? statsPrev : statsA;

        k_project<<<(N + 7) / 8, 256, 0, stream>>>(
            zprev, sPrev, gPrev, bPrev,
            Wk + wo, bk + bo, Wq + wo, bq + bo, Wv + wo, bv + bo, Ws + wo, bs + bo,
            kbuf, (uint4*)qvbuf, zcur, N, do_bn, invN);
        hipMemsetAsync(statsCur, 0, 2048 * sizeof(float), stream);
        k_edges_csr<<<2048, 256, 0, stream>>>(
            off, deg, ssrc, (const float4*)kbuf, (const float4*)qvbuf,
            (const float4*)zprev, sPrev, gPrev, bPrev,
            (float4*)zcur, statsCur, N, (l < 2) ? 1 : 0, do_bn, invN);

        statsPrev = statsCur;
        zprev = zcur;
    }
    k_bn<<<(total + 255) / 256, 256, 0, stream>>>(
        zA, statsA, gamma + 2 * DCH, beta + 2 * DCH, (float*)d_out, total, invN);
}